// Round 11
// baseline (279.127 us; speedup 1.0000x reference)
//
#include <hip/hip_runtime.h>
#include <math.h>
#include <float.h>

#ifndef M_PI
#define M_PI 3.14159265358979323846
#endif

#define N_FFT       512
#define N_BINS      257
#define N_FILTERS   128
#define OUTPUT_SIZE 262144
#define N_TIMESTEPS 128

typedef int int4v __attribute__((ext_vector_type(4)));
typedef float f32x4 __attribute__((ext_vector_type(4)));

// ---- ordered-uint64 encoding for deterministic double atomic min/max ----
__device__ __forceinline__ unsigned long long enc_d(double f) {
    unsigned long long u = (unsigned long long)__double_as_longlong(f);
    return (u & 0x8000000000000000ull) ? ~u : (u | 0x8000000000000000ull);
}
__device__ __forceinline__ double dec_d(unsigned long long e) {
    unsigned long long u = (e & 0x8000000000000000ull) ? (e ^ 0x8000000000000000ull) : ~e;
    return __longlong_as_double((long long)u);
}

// ============================================================================
// K1a: DFT, one block per bin (257 blocks x 64 threads) — verified round 7.
// ============================================================================
__global__ __launch_bounds__(64) void k1a_dft(
    const float* __restrict__ audio, float* __restrict__ mag,
    unsigned long long* __restrict__ minmax)
{
    __shared__ double sre[64];
    __shared__ double sim[64];

    const int b    = blockIdx.x;     // bin 0..256
    const int lane = threadIdx.x;    // 0..63

    double re = 0.0, im = 0.0;
    #pragma unroll
    for (int j = 0; j < 8; ++j) {
        const int n = lane * 8 + j;              // rfft(n=512): first 512 samples
        const int m = (b * n) & (N_FFT - 1);
        double s, c;
        sincos((-2.0 * M_PI * (double)m) / (double)N_FFT, &s, &c);
        const double a = (double)audio[n];
        re += a * c;
        im += a * s;
    }
    sre[lane] = re;
    sim[lane] = im;
    __syncthreads();
    #pragma unroll
    for (int s = 32; s > 0; s >>= 1) {
        if (lane < s) {
            sre[lane] += sre[lane + s];
            sim[lane] += sim[lane + s];
        }
        __syncthreads();
    }
    if (lane == 0) {
        mag[b] = (float)sqrt(sre[0] * sre[0] + sim[0] * sim[0]);
        if (b == 0) {
            minmax[0] = 0xFFFFFFFFFFFFFFFFull;  // min slot
            minmax[1] = 0ull;                   // max slot
        }
    }
}

// ============================================================================
// K2: front-end epilogue (per-block redundant, deterministic) + GEMV.
//   ROUND 12 "waverow" (re-run; round-10 bench was an infra timeout, kernel
//   never ran): fix the COALESCING defect, not the parallelism.
//   Evidence: R11 split-K doubled streams/CU -> FETCH 67->179 MB (1.34x of
//   W!), k2 83.5 us. Root cause: lane-owns-row layout means each wave-load
//   touches 64 scattered 128B lines; line must survive 8 iters to be fully
//   consumed; more waves evict sooner. Fix: 32 lanes SHARE a row — lane s
//   loads W4[row*32+s] -> one wave instruction reads 1KB fully contiguous
//   (2 rows). ad[] hoisted to 4 regs/lane (no LDS in hot loop). Per-lane
//   partial keeps k-ascending fp64 order; 32-lane combine = 5-step
//   __shfl_xor butterfly (commutative adds -> identical bits in all lanes;
//   ~1-ulp reorder vs sequential sum, same class as the verified lo+hi
//   split). 512 blocks x 256 thr = 2048 waves, 128 contiguous rows/wave.
//   Unroll 4 -> 4 coalesced loads in flight/thread.
// ============================================================================
__global__ __launch_bounds__(256) void k2_gemv(
    const f32x4* __restrict__ W4, const float* __restrict__ bias,
    const float* __restrict__ fb, const float* __restrict__ mag,
    const float* __restrict__ adapt, double* __restrict__ activity,
    unsigned long long* __restrict__ minmax)
{
    __shared__ float  magl[N_BINS];
    __shared__ double ad[N_FILTERS];
    __shared__ double red_min[256];
    __shared__ double red_max[256];

    const int tid = threadIdx.x;

    for (int j = tid; j < N_BINS; j += 256) magl[j] = mag[j];
    __syncthreads();

    if (tid < N_FILTERS) {
        const float* row = fb + tid * N_BINS;
        double acc = 0.0;
        int j = 0;
        #pragma unroll 1
        for (int b = 0; b < 8; ++b) {          // 8 x 32 = 256 bins
            float r[32];
            #pragma unroll
            for (int u = 0; u < 32; ++u) r[u] = row[j + u];
            #pragma unroll
            for (int u = 0; u < 32; ++u)
                acc += (double)r[u] * (double)magl[j + u];
            j += 32;
        }
        acc += (double)row[256] * (double)magl[256];   // remainder bin
        const double x = acc + 1e-6;               // + LATENCY_EPSILON
        const double p = pow(x, 0.3);
        const double a = p - (double)adapt[tid] * 0.5;
        ad[tid] = a > 0.0 ? a : 0.0;               // relu
    }
    __syncthreads();

    // ---- waverow GEMV: 32 lanes per row, fully coalesced W reads ----
    const int lane = tid & 63;
    const int sub  = lane & 31;                    // f32x4 slot within row
    const int half = lane >> 5;                    // 0: even row, 1: odd row
    const int wv   = (blockIdx.x * 256 + tid) >> 6;   // 0..2047

    // hoist this lane's ad slice into registers (k-ascending order kept)
    const double ad0 = ad[4 * sub];
    const double ad1 = ad[4 * sub + 1];
    const double ad2 = ad[4 * sub + 2];
    const double ad3 = ad[4 * sub + 3];

    const int row0 = wv * 128 + half;              // this lane's first row
    const f32x4* wp = W4 + (size_t)row0 * 32 + sub;

    double mn = DBL_MAX, mx = -DBL_MAX;
    #pragma unroll 4
    for (int i = 0; i < 64; ++i) {
        const f32x4 w = wp[(size_t)i * 64];        // advance 2 rows/iter
        // per-lane partial, k-ascending
        double p = (double)w[0] * ad0;
        p += (double)w[1] * ad1;
        p += (double)w[2] * ad2;
        p += (double)w[3] * ad3;
        // 32-lane butterfly reduce (within each half-wave group);
        // commutative adds -> every lane of the group gets identical bits
        p += __shfl_xor(p, 1, 64);
        p += __shfl_xor(p, 2, 64);
        p += __shfl_xor(p, 4, 64);
        p += __shfl_xor(p, 8, 64);
        p += __shfl_xor(p, 16, 64);
        const int r = row0 + 2 * i;
        const double a = p + (double)bias[r];
        if (sub == 0) activity[r] = a;
        mn = fmin(mn, a);
        mx = fmax(mx, a);
    }

    red_min[tid] = mn;
    red_max[tid] = mx;
    __syncthreads();
    for (int s = 128; s > 0; s >>= 1) {
        if (tid < s) {
            red_min[tid] = fmin(red_min[tid], red_min[tid + s]);
            red_max[tid] = fmax(red_max[tid], red_max[tid + s]);
        }
        __syncthreads();
    }
    if (tid == 0) {
        atomicMin(&minmax[0], enc_d(red_min[0]));
        atomicMax(&minmax[1], enc_d(red_max[0]));
    }
}

// ============================================================================
// K3: latency coding + spike-matrix write (int32 out), fp64 quantization.
//   At the copy ceiling already (512 MiB @ ~6.7 TB/s ~= 80 us) — leave as is.
// ============================================================================
__global__ __launch_bounds__(256) void k3_spikes(
    const double* __restrict__ activity,
    const unsigned long long* __restrict__ minmax,
    int4v* __restrict__ out4)
{
    const int tid = blockIdx.x * 256 + threadIdx.x;  // 0..65535
    const double amin = dec_d(minmax[0]);
    const double amax = dec_d(minmax[1]);
    const double denom = (amax - amin) + 1e-6;

    const double nx = (activity[4 * tid + 0] - amin) / denom;
    const double ny = (activity[4 * tid + 1] - amin) / denom;
    const double nz = (activity[4 * tid + 2] - amin) / denom;
    const double nw = (activity[4 * tid + 3] - amin) / denom;

    const int lx = (int)((1.0 - nx) * 127.0);
    const int ly = (int)((1.0 - ny) * 127.0);
    const int lz = (int)((1.0 - nz) * 127.0);
    const int lw = (int)((1.0 - nw) * 127.0);

    const int vx = (nx > 0.05) ? 1 : 0;
    const int vy = (ny > 0.05) ? 1 : 0;
    const int vz = (nz > 0.05) ? 1 : 0;
    const int vw = (nw > 0.05) ? 1 : 0;

    const int t0 = blockIdx.y * (N_TIMESTEPS / 4);
    #pragma unroll 8
    for (int t = t0; t < t0 + N_TIMESTEPS / 4; ++t) {
        int4v v;
        v.x = (lx == t) ? vx : 0;
        v.y = (ly == t) ? vy : 0;
        v.z = (lz == t) ? vz : 0;
        v.w = (lw == t) ? vw : 0;
        out4[(size_t)t * (OUTPUT_SIZE / 4) + tid] = v;
    }
}

// ============================================================================
extern "C" void kernel_launch(void* const* d_in, const int* in_sizes, int n_in,
                              void* d_out, int out_size, void* d_ws, size_t ws_size,
                              hipStream_t stream) {
    (void)in_sizes; (void)n_in; (void)out_size; (void)ws_size;

    const float* audio = (const float*)d_in[0];   // [16000]
    const float* fb    = (const float*)d_in[1];   // [128, 257]
    const float* W     = (const float*)d_in[2];   // [262144, 128]
    const float* bias  = (const float*)d_in[3];   // [262144]
    const float* adapt = (const float*)d_in[4];   // [128]
    int* out = (int*)d_out;                       // [128, 262144] bool -> int32

    double* activity = (double*)d_ws;                              // 262144 f64
    unsigned long long* minmax =
        (unsigned long long*)(activity + OUTPUT_SIZE);             // 2 u64
    float* mag = (float*)(minmax + 2);                             // 257 f32

    k1a_dft<<<N_BINS, 64, 0, stream>>>(audio, mag, minmax);
    k2_gemv<<<512, 256, 0, stream>>>(
        (const f32x4*)W, bias, fb, mag, adapt, activity, minmax);
    k3_spikes<<<dim3(OUTPUT_SIZE / 4 / 256, 4), 256, 0, stream>>>(
        activity, minmax, (int4v*)out);
}